// Round 14
// baseline (422.373 us; speedup 1.0000x reference)
//
#include <hip/hip_runtime.h>
#include <hip/hip_bf16.h>

#define B_TOK   4096
#define D_DIM   1024
#define E_NUM   8
#define HID_DIM 512
#define RH_DIM  256
#define EMB_DIM 32
#define NPAIR   (B_TOK * 2)   // 8192
#define CPAD    32            // counts padding: one counter per 128B line

typedef __attribute__((ext_vector_type(8))) short    bf16x8;
typedef __attribute__((ext_vector_type(8))) unsigned short u16x8;
typedef __attribute__((ext_vector_type(4))) unsigned short u16x4;
typedef __attribute__((ext_vector_type(4))) float    f32x4;

__device__ __forceinline__ unsigned short f2bf(float f) {
    union { float f; unsigned u; } v; v.f = f;
    unsigned r = (v.u + 0x7fffu + ((v.u >> 16) & 1u)) >> 16;
    return (unsigned short)r;
}
__device__ __forceinline__ float bf2f(unsigned short b) {
    union { unsigned u; float f; } v; v.u = ((unsigned)b) << 16;
    return v.f;
}

__device__ __forceinline__ void glds16(const void* g, void* l) {
    __builtin_amdgcn_global_load_lds(
        (const __attribute__((address_space(1))) unsigned int*)g,
        (__attribute__((address_space(3))) unsigned int*)l, 16, 0, 0);
}

__device__ inline float apply_act(float v, int a) {
    if (a == 0 || a == 2) return 1.f / (1.f + __expf(-v));                   // sigmoid
    if (a == 1) return fmaxf(v, 0.f) + __logf(1.f + __expf(-fabsf(v)));      // softplus
    return v;                                                                 // identity
}

// ---------------- hx -> bf16 (hi + lo split), layout [token][2048]
__global__ void k_hxbf(const float* __restrict__ h, const float* __restrict__ x,
                       unsigned short* __restrict__ hi, unsigned short* __restrict__ lo) {
    int gid = blockIdx.x * 256 + threadIdx.x;
    int token = gid >> 8;
    int c0 = (gid & 255) * 8;
    const float* src = (c0 < 1024) ? (h + (size_t)token * 1024 + c0)
                                   : (x + (size_t)token * 1024 + c0 - 1024);
    u16x8 oh, ol;
#pragma unroll
    for (int j = 0; j < 8; ++j) {
        float f = src[j];
        unsigned short hb = f2bf(f);
        oh[j] = hb;
        ol[j] = f2bf(f - bf2f(hb));
    }
    size_t o = (size_t)gid * 8;
    *(u16x8*)(hi + o) = oh;
    *(u16x8*)(lo + o) = ol;
}

// ---------------- flat fp32 -> bf16 convert (row-major preserved)
__global__ void k_cvtflat(const float* __restrict__ in, unsigned short* __restrict__ o8) {
    size_t gid = (size_t)blockIdx.x * 256 + threadIdx.x;
    const float4* s = (const float4*)(in + gid * 8);
    float4 a = s[0], b = s[1];
    u16x8 v;
    v[0] = f2bf(a.x); v[1] = f2bf(a.y); v[2] = f2bf(a.z); v[3] = f2bf(a.w);
    v[4] = f2bf(b.x); v[5] = f2bf(b.y); v[6] = f2bf(b.z); v[7] = f2bf(b.w);
    *(u16x8*)(o8 + gid * 8) = v;
}

// ---------------- W [K][N] fp32 -> permuted bf16 [K/8][N][8]; z = m*eper + e
template<bool SPLIT>
__global__ void k_convW(const float* __restrict__ in0, const float* __restrict__ in1,
                        const float* __restrict__ in2, const float* __restrict__ in3,
                        unsigned short* __restrict__ oh, unsigned short* __restrict__ ol,
                        int K, int N, int eper) {
    int z = blockIdx.z;
    int e = z % eper, m = z / eper;
    const float* in = (m == 0 ? in0 : m == 1 ? in1 : m == 2 ? in2 : in3) + (size_t)e * K * N;
    int n  = blockIdx.x * 256 + threadIdx.x;
    int kg = blockIdx.y;
    const float* ip = in + (size_t)kg * 8 * N + n;
    u16x8 hv, lv;
#pragma unroll
    for (int j = 0; j < 8; ++j) {
        float f = ip[(size_t)j * N];
        unsigned short hb = f2bf(f);
        hv[j] = hb;
        if (SPLIT) lv[j] = f2bf(f - bf2f(hb));
    }
    size_t o = (size_t)z * K * N + ((size_t)kg * N + n) * 8;
    *(u16x8*)(oh + o) = hv;
    if (SPLIT) *(u16x8*)(ol + o) = lv;
}

// ---------------- fused bias: bfused[e][o*1024+col] = b2[e][o-slice]@Wo + bo[e]
__global__ void k_bfuse(const float* __restrict__ b2,
                        const float* __restrict__ bo0, const float* __restrict__ bo1,
                        const float* __restrict__ bo2, const float* __restrict__ bo3,
                        const unsigned short* __restrict__ wsc,
                        float* __restrict__ bfused) {
    int zp = blockIdx.y; int e = zp & 7, o = zp >> 3;
    int col = blockIdx.x * 256 + threadIdx.x;
    __shared__ float b2s[1024];
    for (int i = threadIdx.x; i < 1024; i += 256)
        b2s[i] = b2[(size_t)e * 4096 + o * 1024 + i];
    __syncthreads();
    const unsigned short* W = wsc + (size_t)zp * 1024 * 1024;
    float acc = 0.f;
    for (int dg = 0; dg < 128; ++dg) {
        u16x8 w = *(const u16x8*)&W[((size_t)dg * 1024 + col) * 8];
#pragma unroll
        for (int j = 0; j < 8; ++j) acc += b2s[dg * 8 + j] * bf2f(w[j]);
    }
    const float* bo = (o == 0) ? bo0 : (o == 1) ? bo1 : (o == 2) ? bo2 : bo3;
    bfused[(size_t)e * 4096 + o * 1024 + col] = acc + bo[(size_t)e * 1024 + col];
}

// ---------------- routing tail: rconst inline + split-K partial sum + LN +
// gelu + logits(parallel) + top2 + lists (PADDED counters, split atomics)
__global__ void k_route(const float* __restrict__ Pf,
                        const int* __restrict__ lidx,
                        const float* __restrict__ layer_emb,
                        const float* __restrict__ phase_emb,
                        const float* __restrict__ Wr1, const float* __restrict__ br1,
                        const float* __restrict__ lnr_g, const float* __restrict__ lnr_b,
                        const float* __restrict__ Wr2, const float* __restrict__ br2,
                        float* __restrict__ pair_w,
                        int* __restrict__ lists, int* __restrict__ counts) {
    int b = blockIdx.x, t = threadIdx.x;
    __shared__ float sv[RH_DIM];
    __shared__ float a1[4], a2[4], mv[2];
    __shared__ float wsum[4][E_NUM];
    __shared__ float lg[E_NUM];
    __shared__ int sei[2];

    float rc = br1[t];
    {
        int li = lidx[0];
        for (int k = 0; k < EMB_DIM; ++k)
            rc += layer_emb[li * EMB_DIM + k] * Wr1[(2048 + k) * RH_DIM + t];
        for (int k = 0; k < EMB_DIM; ++k)
            rc += phase_emb[k] * Wr1[(2080 + k) * RH_DIM + t];
    }

    size_t idx = (size_t)b * RH_DIM + t;
    const size_t kstride = (size_t)B_TOK * RH_DIM;
    float y = ((Pf[idx] + Pf[idx + kstride]) + (Pf[idx + 2 * kstride] + Pf[idx + 3 * kstride]))
              + rc;
    float s1 = y, s2 = y * y;
    for (int o = 32; o; o >>= 1) { s1 += __shfl_down(s1, o); s2 += __shfl_down(s2, o); }
    if ((t & 63) == 0) { a1[t >> 6] = s1; a2[t >> 6] = s2; }
    __syncthreads();
    if (t == 0) {
        float S1 = a1[0] + a1[1] + a1[2] + a1[3];
        float S2 = a2[0] + a2[1] + a2[2] + a2[3];
        float mu = S1 / 256.f;
        mv[0] = mu;
        mv[1] = rsqrtf(S2 / 256.f - mu * mu + 1e-5f);
    }
    __syncthreads();
    float n = (y - mv[0]) * mv[1] * lnr_g[t] + lnr_b[t];
    sv[t] = 0.5f * n * (1.f + erff(n * 0.70710678118654752f));
    __syncthreads();

    {
        int e = t & 7, c = t >> 3;
        float part = 0.f;
#pragma unroll
        for (int jj = 0; jj < 8; ++jj)
            part += sv[c * 8 + jj] * Wr2[(c * 8 + jj) * E_NUM + e];
        part += __shfl_down(part, 8);
        part += __shfl_down(part, 16);
        part += __shfl_down(part, 32);
        if ((t & 63) < 8) wsum[t >> 6][e] = part;
    }
    __syncthreads();
    if (t < E_NUM)
        lg[t] = br2[t] + wsum[0][t] + wsum[1][t] + wsum[2][t] + wsum[3][t];
    __syncthreads();
    if (t == 0) {
        float v0 = -1e30f; int i0 = 0;
        for (int e = 0; e < E_NUM; ++e) if (lg[e] > v0) { v0 = lg[e]; i0 = e; }
        float v1 = -1e30f; int i1 = 0;
        for (int e = 0; e < E_NUM; ++e) if (e != i0 && lg[e] > v1) { v1 = lg[e]; i1 = e; }
        float e1 = expf(v1 - v0);
        pair_w[2 * b] = 1.f / (1.f + e1);
        pair_w[2 * b + 1] = e1 / (1.f + e1);
        sei[0] = i0; sei[1] = i1;
    }
    __syncthreads();
    if (t < 2) {
        int e = sei[t];
        int pos = atomicAdd(&counts[e * CPAD], 1);
        lists[e * B_TOK + pos] = 2 * b + t;
    }
}

// ---------------- sorted-row metadata (offs computed inline from padded counts)
__global__ void k_meta(const int* __restrict__ counts, const int* __restrict__ lists,
                       int* __restrict__ rowmap, int* __restrict__ row_e,
                       int* __restrict__ qof) {
    int q = blockIdx.x * 256 + threadIdx.x;
    int off_[E_NUM + 1]; off_[0] = 0;
#pragma unroll
    for (int i = 0; i < E_NUM; ++i) off_[i + 1] = off_[i] + counts[i * CPAD];
    int e = 0;
    while (e < E_NUM - 1 && q >= off_[e + 1]) ++e;
    int p = lists[e * B_TOK + (q - off_[e])];
    rowmap[q] = p;
    row_e[q] = e;
    qof[p] = q;
}

// ---------------- combine layer1 split-K partials + bias, LN + gelu -> bf16
__global__ void k_lngelu(const float* __restrict__ hidp, const float* __restrict__ b1,
                         unsigned short* __restrict__ hidb, const int* __restrict__ row_e,
                         const float* __restrict__ g, const float* __restrict__ bb) {
    int q = blockIdx.x, t = threadIdx.x;
    int e = row_e[q];
    const size_t st = (size_t)NPAIR * HID_DIM;
    size_t o0 = (size_t)q * HID_DIM + t;
    float y0 = hidp[o0] + hidp[o0 + st] + b1[e * HID_DIM + t];
    float y1 = hidp[o0 + 256] + hidp[o0 + 256 + st] + b1[e * HID_DIM + t + 256];
    float s1 = y0 + y1, s2 = y0 * y0 + y1 * y1;
    for (int o = 32; o; o >>= 1) { s1 += __shfl_down(s1, o); s2 += __shfl_down(s2, o); }
    __shared__ float a1[4], a2[4], mv[2];
    if ((t & 63) == 0) { a1[t >> 6] = s1; a2[t >> 6] = s2; }
    __syncthreads();
    if (t == 0) {
        float S1 = a1[0] + a1[1] + a1[2] + a1[3];
        float S2 = a2[0] + a2[1] + a2[2] + a2[3];
        float mu = S1 / 512.f;
        mv[0] = mu;
        mv[1] = rsqrtf(S2 / 512.f - mu * mu + 1e-5f);
    }
    __syncthreads();
    const float* ge = g + e * HID_DIM;
    const float* be = bb + e * HID_DIM;
    float mu = mv[0], ir = mv[1];
    float n0 = (y0 - mu) * ir * ge[t] + be[t];
    float n1 = (y1 - mu) * ir * ge[t + 256] + be[t + 256];
    unsigned short* orow = hidb + (size_t)q * HID_DIM;
    orow[t]       = f2bf(0.5f * n0 * (1.f + erff(n0 * 0.70710678118654752f)));
    orow[t + 256] = f2bf(0.5f * n1 * (1.f + erff(n1 * 0.70710678118654752f)));
}

// ---------------- final combine: out[o][token] = w0*act(sel[q0]) + w1*act(sel[q1])
__global__ void k_comb(const unsigned short* __restrict__ sel,
                       const int* __restrict__ qof, const float* __restrict__ pw,
                       float* __restrict__ out) {
    int b = blockIdx.x, o = blockIdx.y;
    int c = threadIdx.x * 4;
    int q0 = qof[2 * b], q1 = qof[2 * b + 1];
    float w0 = pw[2 * b], w1 = pw[2 * b + 1];
    u16x4 a = __builtin_nontemporal_load((const u16x4*)(sel + (size_t)q0 * 4096 + o * 1024 + c));
    u16x4 bq = __builtin_nontemporal_load((const u16x4*)(sel + (size_t)q1 * 4096 + o * 1024 + c));
    f32x4 r;
#pragma unroll
    for (int j = 0; j < 4; ++j)
        r[j] = w0 * apply_act(bf2f(a[j]), o) + w1 * apply_act(bf2f(bq[j]), o);
    __builtin_nontemporal_store(r, (f32x4*)(out + ((size_t)o * B_TOK + b) * D_DIM + c));
}

// ---------------- bf16 MFMA grouped GEMM, 128x128x32 tile, 4 waves
// R13-winning loop (NBUF=2, ONE barrier/iter, 32KB LDS, setprio, slot-XOR)
// + m-tile GRID-STRIDE loop (gy sized to live tiles; loops for safety) so no
//   dead-block dispatch dilutes residency
// + MODE 1 N-split: z = nh*8+e, each z covers cols [nh*N, nh*N+N) of Nfull
//   (2MB weight panels -> L2-resident under the sel store stream)
// MODE 1: Cb[q*ldc + ncb+col] = bf16(acc+bias)  (sorted rows; -> sel)
// MODE 4: Cf[(kh*B_TOK + row)*ldc] = acc        (dense rows, z = kh)
// MODE 5: Cf[(kh*NPAIR + q)*ldc]  = acc         (sorted rows, z = kh*8+e)
// MODE 8: Wfused-permuted write: A rows at e*512 offset, z = o*8+e
// MODE 9: fallback: atomic out[o][token] += pw*act(acc+bias)
template<int MODE, bool SPLIT, bool AGATHER, bool ZPIN>
__global__ __launch_bounds__(256)
void k_mm(const unsigned short* __restrict__ A, const unsigned short* __restrict__ Alo,
          int lda, int rowshift, int acol0,
          const unsigned short* __restrict__ Wp, const unsigned short* __restrict__ Wlo,
          size_t wstride,
          const float* __restrict__ bias, int bstride,
          float* __restrict__ Cf, unsigned short* __restrict__ Cb, int ldc,
          const int* __restrict__ counts, const int* __restrict__ rowmap, int Mfix,
          int N, int Nfull, int Kdim, int nz_e,
          float* __restrict__ outp, const float* __restrict__ pw) {
    const int gx = gridDim.x, gy = gridDim.y;
    unsigned fb = blockIdx.x + gx * (blockIdx.y + gy * blockIdx.z);
    int bx, byy, bz;
    if (ZPIN) {
        const unsigned nmn = gx * gy;
        unsigned xcd = fb & 7u, s = fb >> 3;
        bz  = xcd + 8u * (s / nmn);
        unsigned inner = s % nmn;
        bx  = inner % gx;
        byy = inner / gx;
    } else {
        unsigned xcd = fb & 7u, sb = fb >> 3;
        unsigned G = xcd + 8u * (sb / gx);
        bx  = sb % gx;
        byy = G % gy;
        bz  = G / gy;
    }

    const int e  = bz % nz_e;
    const int zq = bz / nz_e;
    int cnt = Mfix, base = 0;
    if (counts) {
        cnt = 0;
#pragma unroll
        for (int i = 0; i < E_NUM; ++i) {
            int c = counts[i * CPAD];
            if (i < e) base += c;
            if (i == e) cnt = c;
        }
    }
    const int n0 = bx * 128;

    const size_t woff = (MODE == 8) ? (size_t)bz * wstride
                      : (MODE == 1 || MODE == 9) ? (size_t)e * wstride
                      : (size_t)e * wstride + (size_t)zq * Kdim * N;
    const unsigned short* W  = Wp + woff;
    const unsigned short* Wl = SPLIT ? (Wlo + woff) : nullptr;
    const float* bptr = (MODE == 1 || MODE == 9) ? bias + (size_t)e * bstride : nullptr;
    const int acol = acol0 + ((MODE == 4 || MODE == 5 || MODE == 8) ? zq * Kdim : 0);
    const int ncb  = (MODE == 1) ? zq * N : 0;   // column base for the N-split half

    constexpr int ABUF = SPLIT ? 8192 : 4096;
    __shared__ unsigned short Alds[2][ABUF];
    __shared__ unsigned short Blds[2][ABUF];

    const int tid  = threadIdx.x;
    const int lane = tid & 63;
    const int wid  = tid >> 6;
    const int c0 = tid, c1 = tid + 256;
    const int r0 = c0 >> 2, r1 = c1 >> 2;

    const int wm = wid >> 1, wn = wid & 1;
    const int lr = lane & 15, lg = lane >> 4;
    const int aslot = (lg ^ ((lr >> 1) & 3)) << 3;
    const int d0 = c0 * 8, d1 = c1 * 8;
    const size_t bstep = (size_t)32 * Nfull;

    // ---- m-tile grid-stride loop (all waves in the block agree on the count)
    for (int mt = byy; mt * 128 < cnt; mt += gy) {
        const int m0 = mt * 128;

        auto aoff_of = [&](int r, int cq) -> size_t {
            int rr = m0 + r; if (rr >= cnt) rr = cnt - 1;
            int qg = base + rr;
            int row = AGATHER ? (rowmap[qg] >> rowshift)
                              : (MODE == 8 ? e * 512 + qg : qg);
            int slot = cq ^ ((r >> 1) & 3);
            return (size_t)row * lda + acol + (slot << 3);
        };
        size_t aoff0 = aoff_of(r0, c0 & 3);
        size_t aoff1 = aoff_of(r1, c1 & 3);
        const unsigned short* a0 = A + aoff0;
        const unsigned short* a1 = A + aoff1;
        const unsigned short* al0 = SPLIT ? Alo + aoff0 : nullptr;
        const unsigned short* al1 = SPLIT ? Alo + aoff1 : nullptr;
        size_t boff0 = ((size_t)(c0 >> 7) * Nfull + ncb + n0 + (c0 & 127)) * 8;
        size_t boff1 = ((size_t)(c1 >> 7) * Nfull + ncb + n0 + (c1 & 127)) * 8;
        const unsigned short* b0 = W + boff0;
        const unsigned short* b1 = W + boff1;
        const unsigned short* bl0 = SPLIT ? Wl + boff0 : nullptr;
        const unsigned short* bl1 = SPLIT ? Wl + boff1 : nullptr;

        auto stage = [&](int buf) {
            glds16(a0, &Alds[buf][d0]);
            glds16(a1, &Alds[buf][d1]);
            glds16(b0, &Blds[buf][d0]);
            glds16(b1, &Blds[buf][d1]);
            if constexpr (SPLIT) {
                glds16(al0, &Alds[buf][4096 + d0]);
                glds16(al1, &Alds[buf][4096 + d1]);
                glds16(bl0, &Blds[buf][4096 + d0]);
                glds16(bl1, &Blds[buf][4096 + d1]);
                al0 += 32; al1 += 32; bl0 += bstep; bl1 += bstep;
            }
            a0 += 32; a1 += 32; b0 += bstep; b1 += bstep;
        };

        f32x4 acc[4][4];
#pragma unroll
        for (int i = 0; i < 4; ++i)
#pragma unroll
            for (int j = 0; j < 4; ++j) acc[i][j] = (f32x4){0.f, 0.f, 0.f, 0.f};

        auto compute = [&](int b) {
            bf16x8 af[4], bfr[4];
#pragma unroll
            for (int i = 0; i < 4; ++i)
                af[i] = *(const bf16x8*)&Alds[b][(wm * 64 + i * 16 + lr) * 32 + aslot];
#pragma unroll
            for (int i = 0; i < 4; ++i)
                bfr[i] = *(const bf16x8*)&Blds[b][((lg << 7) + wn * 64 + i * 16 + lr) * 8];
            __builtin_amdgcn_s_setprio(1);
#pragma unroll
            for (int mi = 0; mi < 4; ++mi)
#pragma unroll
                for (int ni = 0; ni < 4; ++ni)
                    acc[mi][ni] = __builtin_amdgcn_mfma_f32_16x16x32_bf16(af[mi], bfr[ni], acc[mi][ni], 0, 0, 0);
            if constexpr (SPLIT) {
                bf16x8 afl[4], bfl[4];
#pragma unroll
                for (int i = 0; i < 4; ++i)
                    afl[i] = *(const bf16x8*)&Alds[b][4096 + (wm * 64 + i * 16 + lr) * 32 + aslot];
#pragma unroll
                for (int i = 0; i < 4; ++i)
                    bfl[i] = *(const bf16x8*)&Blds[b][4096 + ((lg << 7) + wn * 64 + i * 16 + lr) * 8];
#pragma unroll
                for (int mi = 0; mi < 4; ++mi)
#pragma unroll
                    for (int ni = 0; ni < 4; ++ni) {
                        acc[mi][ni] = __builtin_amdgcn_mfma_f32_16x16x32_bf16(af[mi],  bfl[ni], acc[mi][ni], 0, 0, 0);
                        acc[mi][ni] = __builtin_amdgcn_mfma_f32_16x16x32_bf16(afl[mi], bfr[ni], acc[mi][ni], 0, 0, 0);
                    }
            }
            __builtin_amdgcn_s_setprio(0);
            __builtin_amdgcn_sched_barrier(0);
        };

        const int niter = Kdim / 32;
        stage(0);
        asm volatile("s_waitcnt vmcnt(0)" ::: "memory");
        __builtin_amdgcn_s_barrier();
        __builtin_amdgcn_sched_barrier(0);
        int cur = 0;
        for (int it = 0; it < niter; ++it) {
            const bool more = (it + 1 < niter);
            if (more) stage(cur ^ 1);
            compute(cur);
            if (more) {
                asm volatile("s_waitcnt vmcnt(0)" ::: "memory");
                __builtin_amdgcn_s_barrier();
                __builtin_amdgcn_sched_barrier(0);
            }
            cur ^= 1;
        }
        // all waves finished reading LDS for this m-tile before next stage(0):
        __builtin_amdgcn_s_barrier();

        float bv[4];
#pragma unroll
        for (int ni = 0; ni < 4; ++ni)
            bv[ni] = (MODE == 1 || MODE == 9) ? bptr[ncb + n0 + wn * 64 + ni * 16 + lr] : 0.f;

#pragma unroll
        for (int mi = 0; mi < 4; ++mi) {
            int rbase = m0 + wm * 64 + mi * 16 + lg * 4;
#pragma unroll
            for (int rg = 0; rg < 4; ++rg) {
                int r = rbase + rg;
                if (r >= cnt) continue;
                int q = base + r;
#pragma unroll
                for (int ni = 0; ni < 4; ++ni) {
                    int col = ncb + n0 + wn * 64 + ni * 16 + lr;
                    float v = acc[mi][ni][rg] + bv[ni];
                    if (MODE == 1) {
                        Cb[(size_t)q * ldc + col] = f2bf(v);
                    } else if (MODE == 4) {
                        Cf[((size_t)zq * B_TOK + q) * ldc + col] = v;
                    } else if (MODE == 5) {
                        Cf[((size_t)zq * NPAIR + q) * ldc + col] = v;
                    } else if (MODE == 8) {
                        Cb[((size_t)e * 64 * 4096 + (size_t)(r >> 3) * 4096 + acol + col) * 8
                           + (r & 7)] = f2bf(v);
                    } else {  // MODE 9 fallback
                        int p = rowmap[q];
                        int o = col >> 10;
                        atomicAdd(outp + ((size_t)o * B_TOK + (p >> 1)) * D_DIM + (col & 1023),
                                  pw[p] * apply_act(v, o));
                    }
                }
            }
        }
    }
}

extern "C" void kernel_launch(void* const* d_in, const int* in_sizes, int n_in,
                              void* d_out, int out_size, void* d_ws, size_t ws_size,
                              hipStream_t stream) {
    const float* h         = (const float*)d_in[0];
    const float* x         = (const float*)d_in[1];
    const int*   lidx      = (const int*)d_in[2];
    const float* layer_emb = (const float*)d_in[3];
    const float* phase_emb = (const float*)d_in[4];
    const float* Wr1       = (const float*)d_in[5];
    const float* br1       = (const float*)d_in[6];
    const float* lnr_g     = (const float*)d_in[7];
    const float* lnr_b     = (const float*)d_in[8];
    const float* Wr2       = (const float*)d_in[9];
    const float* br2       = (const float*)d_in[10];
    const float* W1        = (const float*)d_in[11];
    const float* b1        = (const float*)d_in[12];
    const float* ln1g      = (const float*)d_in[13];
    const float* ln1b      = (const float*)d_in[14];
    const float* W2        = (const float*)d_in[15];
    const float* b2        = (const float*)d_in[16];
    const float* Wa        = (const float*)d_in[17];
    const float* ba        = (const float*)d_in[18];
    const float* Wb_       = (const float*)d_in[19];
    const float* bbv       = (const float*)d_in[20];
    const float* Wg        = (const float*)d_in[21];
    const float* bg        = (const float*)d_in[22];
    const float* Wv        = (const float*)d_in[23];
    const float* bv        = (const float*)d_in[24];
    float* out = (float*)d_out;

    char* ws = (char*)d_ws;
    size_t off = 0;
    auto alloc = [&](size_t nb) { void* p = ws + off; off = (off + nb + 255) & ~(size_t)255; return p; };
    float*          pair_w  = (float*)alloc(NPAIR * 4);
    int*            counts  = (int*)alloc(E_NUM * CPAD * 4);                       // padded: 1KB
    int*            lists   = (int*)alloc((size_t)E_NUM * B_TOK * 4);
    int*            rowmap  = (int*)alloc(NPAIR * 4);
    int*            row_e   = (int*)alloc(NPAIR * 4);
    int*            qof     = (int*)alloc(NPAIR * 4);
    float*          bfused  = (float*)alloc((size_t)E_NUM * 4096 * 4);             // 128 KB
    unsigned short* hx_hi   = (unsigned short*)alloc((size_t)B_TOK * 2048 * 2);    // 16 MiB
    unsigned short* hid_bf  = (unsigned short*)alloc((size_t)NPAIR * HID_DIM * 2); // 8 MiB
    unsigned short* wsc_hi  = (unsigned short*)alloc((size_t)8 * 2048 * HID_DIM * 2); // 16 MiB
    unsigned short* wsc_lo  = (unsigned short*)alloc((size_t)2048 * RH_DIM * 2);   // 1 MiB
    unsigned short* Wfused  = (unsigned short*)alloc((size_t)E_NUM * 64 * 4096 * 8 * 2); // 32 MiB
    unsigned short* sel     = (unsigned short*)alloc((size_t)NPAIR * 4096 * 2);    // 64 MiB
    char*           scratch = (char*)alloc((size_t)34 << 20);                      // 34 MiB
    const bool use_sel = (off <= ws_size);
    // aliases (disjoint lifetimes):
    unsigned short* wsc4  = sel;                                         // 64M: layer3 W conv, dead before sel write
    unsigned short* W2bf  = (unsigned short*)scratch;                    // 33.5M, written after hidp dead
    unsigned short* hx_lo = (unsigned short*)scratch;                    // 16M, dead after routing mm
    float*          Pf    = (float*)(scratch + ((size_t)17 << 20));      // 16M, dead after k_route
    float*          hidp  = (float*)scratch;                             // 33.6M, dead after k_lngelu

    if (!use_sel) (void)hipMemsetAsync(d_out, 0, (size_t)out_size * 4, stream);
    (void)hipMemsetAsync(counts, 0, E_NUM * CPAD * 4, stream);

    // ---- routing path: split-K x4 partials (deterministic fixed-order combine)
    k_hxbf<<<4096, 256, 0, stream>>>(h, x, hx_hi, hx_lo);
    k_convW<true><<<dim3(1, 256, 1), 256, 0, stream>>>(Wr1, nullptr, nullptr, nullptr,
                                                       wsc_hi, wsc_lo, 2048, RH_DIM, 1);
    k_mm<4, true, false, false><<<dim3(2, 32, 4), 256, 0, stream>>>(
        hx_hi, hx_lo, 2048, 0, 0, wsc_hi, wsc_lo, 0, nullptr, 0,
        Pf, nullptr, RH_DIM, nullptr, nullptr, B_TOK,
        RH_DIM, RH_DIM, 512, 1, nullptr, nullptr);
    k_route<<<B_TOK, 256, 0, stream>>>(Pf, lidx, layer_emb, phase_emb, Wr1, br1,
                                       lnr_g, lnr_b, Wr2, br2,
                                       pair_w, lists, counts);
    k_meta<<<NPAIR / 256, 256, 0, stream>>>(counts, lists, rowmap, row_e, qof);

    // ---- layer1 (split-K x2, sorted C, gy=9 live-tile grid):
    k_convW<false><<<dim3(2, 256, 8), 256, 0, stream>>>(W1, nullptr, nullptr, nullptr,
                                                        wsc_hi, nullptr, 2048, HID_DIM, 8);
    k_mm<5, false, true, true><<<dim3(4, 9, 16), 256, 0, stream>>>(
        hx_hi, nullptr, 2048, 1, 0, wsc_hi, nullptr, (size_t)2048 * HID_DIM, nullptr, 0,
        hidp, nullptr, HID_DIM, counts, rowmap, 0,
        HID_DIM, HID_DIM, 1024, 8, nullptr, nullptr);
    k_lngelu<<<NPAIR, 256, 0, stream>>>(hidp, b1, hid_bf, row_e, ln1g, ln1b);

    // ---- Wfused precompute: Wfused[e] = W2[e] (512x4096, o-sliced) @ Wo[e]
    k_cvtflat<<<8192, 256, 0, stream>>>(W2, W2bf);
    k_convW<false><<<dim3(4, 128, 32), 256, 0, stream>>>(
        Wa, Wb_, Wg, Wv, wsc4, nullptr, D_DIM, D_DIM, 8);
    k_bfuse<<<dim3(4, 32), 256, 0, stream>>>(b2, ba, bbv, bg, bv, wsc4, bfused);
    k_mm<8, false, false, true><<<dim3(8, 4, 32), 256, 0, stream>>>(
        W2bf, nullptr, 4096, 0, 0,
        wsc4, nullptr, (size_t)D_DIM * D_DIM, nullptr, 0,
        nullptr, Wfused, 0, nullptr, nullptr, 512,
        D_DIM, D_DIM, D_DIM, 8, nullptr, nullptr);

    // ---- fused layer2+3 (N-split x2, gy=9): sel[q][ncb..ncb+2048) per z
    if (use_sel) {
        k_mm<1, false, false, true><<<dim3(16, 9, 16), 256, 0, stream>>>(
            hid_bf, nullptr, HID_DIM, 0, 0,
            Wfused, nullptr, (size_t)64 * 4096 * 8, bfused, 4096,
            nullptr, sel, 4096, counts, rowmap, 0,
            2048, 4096, HID_DIM, 8, nullptr, nullptr);
        k_comb<<<dim3(B_TOK, 4), 256, 0, stream>>>(sel, qof, pair_w, out);
    } else {
        k_mm<9, false, false, true><<<dim3(32, 32, 8), 256, 0, stream>>>(
            hid_bf, nullptr, HID_DIM, 0, 0,
            Wfused, nullptr, (size_t)64 * 4096 * 8, bfused, 4096,
            nullptr, nullptr, 0, counts, rowmap, 0,
            4096, 4096, HID_DIM, 8, out, pair_w);
    }
}

// Round 15
// 398.289 us; speedup vs baseline: 1.0605x; 1.0605x over previous
//
#include <hip/hip_runtime.h>
#include <hip/hip_bf16.h>

#define B_TOK   4096
#define D_DIM   1024
#define E_NUM   8
#define HID_DIM 512
#define RH_DIM  256
#define EMB_DIM 32
#define NPAIR   (B_TOK * 2)   // 8192
#define CPAD    32            // counts padding: one counter per 128B line

typedef __attribute__((ext_vector_type(8))) short    bf16x8;
typedef __attribute__((ext_vector_type(8))) unsigned short u16x8;
typedef __attribute__((ext_vector_type(4))) unsigned short u16x4;
typedef __attribute__((ext_vector_type(4))) float    f32x4;

__device__ __forceinline__ unsigned short f2bf(float f) {
    union { float f; unsigned u; } v; v.f = f;
    unsigned r = (v.u + 0x7fffu + ((v.u >> 16) & 1u)) >> 16;
    return (unsigned short)r;
}
__device__ __forceinline__ float bf2f(unsigned short b) {
    union { unsigned u; float f; } v; v.u = ((unsigned)b) << 16;
    return v.f;
}

__device__ __forceinline__ void glds16(const void* g, void* l) {
    __builtin_amdgcn_global_load_lds(
        (const __attribute__((address_space(1))) unsigned int*)g,
        (__attribute__((address_space(3))) unsigned int*)l, 16, 0, 0);
}

__device__ inline float apply_act(float v, int a) {
    if (a == 0 || a == 2) return 1.f / (1.f + __expf(-v));                   // sigmoid
    if (a == 1) return fmaxf(v, 0.f) + __logf(1.f + __expf(-fabsf(v)));      // softplus
    return v;                                                                 // identity
}

// ---------------- hx -> bf16 (hi + lo split), layout [token][2048]
__global__ void k_hxbf(const float* __restrict__ h, const float* __restrict__ x,
                       unsigned short* __restrict__ hi, unsigned short* __restrict__ lo) {
    int gid = blockIdx.x * 256 + threadIdx.x;
    int token = gid >> 8;
    int c0 = (gid & 255) * 8;
    const float* src = (c0 < 1024) ? (h + (size_t)token * 1024 + c0)
                                   : (x + (size_t)token * 1024 + c0 - 1024);
    u16x8 oh, ol;
#pragma unroll
    for (int j = 0; j < 8; ++j) {
        float f = src[j];
        unsigned short hb = f2bf(f);
        oh[j] = hb;
        ol[j] = f2bf(f - bf2f(hb));
    }
    size_t o = (size_t)gid * 8;
    *(u16x8*)(hi + o) = oh;
    *(u16x8*)(lo + o) = ol;
}

// ---------------- flat fp32 -> bf16 convert (row-major preserved)
__global__ void k_cvtflat(const float* __restrict__ in, unsigned short* __restrict__ o8) {
    size_t gid = (size_t)blockIdx.x * 256 + threadIdx.x;
    const float4* s = (const float4*)(in + gid * 8);
    float4 a = s[0], b = s[1];
    u16x8 v;
    v[0] = f2bf(a.x); v[1] = f2bf(a.y); v[2] = f2bf(a.z); v[3] = f2bf(a.w);
    v[4] = f2bf(b.x); v[5] = f2bf(b.y); v[6] = f2bf(b.z); v[7] = f2bf(b.w);
    *(u16x8*)(o8 + gid * 8) = v;
}

// ---------------- W [K][N] fp32 -> permuted bf16 [K/8][N][8]; z = m*eper + e
template<bool SPLIT>
__global__ void k_convW(const float* __restrict__ in0, const float* __restrict__ in1,
                        const float* __restrict__ in2, const float* __restrict__ in3,
                        unsigned short* __restrict__ oh, unsigned short* __restrict__ ol,
                        int K, int N, int eper) {
    int z = blockIdx.z;
    int e = z % eper, m = z / eper;
    const float* in = (m == 0 ? in0 : m == 1 ? in1 : m == 2 ? in2 : in3) + (size_t)e * K * N;
    int n  = blockIdx.x * 256 + threadIdx.x;
    int kg = blockIdx.y;
    const float* ip = in + (size_t)kg * 8 * N + n;
    u16x8 hv, lv;
#pragma unroll
    for (int j = 0; j < 8; ++j) {
        float f = ip[(size_t)j * N];
        unsigned short hb = f2bf(f);
        hv[j] = hb;
        if (SPLIT) lv[j] = f2bf(f - bf2f(hb));
    }
    size_t o = (size_t)z * K * N + ((size_t)kg * N + n) * 8;
    *(u16x8*)(oh + o) = hv;
    if (SPLIT) *(u16x8*)(ol + o) = lv;
}

// ---------------- fused bias: bfused[e][o*1024+col] = b2[e][o-slice]@Wo + bo[e]
__global__ void k_bfuse(const float* __restrict__ b2,
                        const float* __restrict__ bo0, const float* __restrict__ bo1,
                        const float* __restrict__ bo2, const float* __restrict__ bo3,
                        const unsigned short* __restrict__ wsc,
                        float* __restrict__ bfused) {
    int zp = blockIdx.y; int e = zp & 7, o = zp >> 3;
    int col = blockIdx.x * 256 + threadIdx.x;
    __shared__ float b2s[1024];
    for (int i = threadIdx.x; i < 1024; i += 256)
        b2s[i] = b2[(size_t)e * 4096 + o * 1024 + i];
    __syncthreads();
    const unsigned short* W = wsc + (size_t)zp * 1024 * 1024;
    float acc = 0.f;
    for (int dg = 0; dg < 128; ++dg) {
        u16x8 w = *(const u16x8*)&W[((size_t)dg * 1024 + col) * 8];
#pragma unroll
        for (int j = 0; j < 8; ++j) acc += b2s[dg * 8 + j] * bf2f(w[j]);
    }
    const float* bo = (o == 0) ? bo0 : (o == 1) ? bo1 : (o == 2) ? bo2 : bo3;
    bfused[(size_t)e * 4096 + o * 1024 + col] = acc + bo[(size_t)e * 1024 + col];
}

// ---------------- routing const: br1 + le@Wr1[2048:2080] + pe@Wr1[2080:2112]
__global__ void k_rconst(const float* __restrict__ layer_emb,
                         const float* __restrict__ phase_emb,
                         const int* __restrict__ lidx,
                         const float* __restrict__ Wr1,
                         const float* __restrict__ br1,
                         float* __restrict__ rconst) {
    int j = threadIdx.x;
    int li = lidx[0];
    float acc = br1[j];
    for (int t = 0; t < EMB_DIM; ++t)
        acc += layer_emb[li * EMB_DIM + t] * Wr1[(2048 + t) * RH_DIM + j];
    for (int t = 0; t < EMB_DIM; ++t)
        acc += phase_emb[t] * Wr1[(2080 + t) * RH_DIM + j];
    rconst[j] = acc;
}

// ---------------- routing tail: split-K partial sum + rconst + LN + gelu +
// logits(parallel) + top2 + lists (PADDED counters, split atomics)
__global__ void k_route(const float* __restrict__ Pf, const float* __restrict__ rconst,
                        const float* __restrict__ lnr_g, const float* __restrict__ lnr_b,
                        const float* __restrict__ Wr2, const float* __restrict__ br2,
                        float* __restrict__ pair_w,
                        int* __restrict__ lists, int* __restrict__ counts) {
    int b = blockIdx.x, t = threadIdx.x;
    __shared__ float sv[RH_DIM];
    __shared__ float a1[4], a2[4], mv[2];
    __shared__ float wsum[4][E_NUM];
    __shared__ float lg[E_NUM];
    __shared__ int sei[2];

    size_t idx = (size_t)b * RH_DIM + t;
    const size_t kstride = (size_t)B_TOK * RH_DIM;
    float y = ((Pf[idx] + Pf[idx + kstride]) + (Pf[idx + 2 * kstride] + Pf[idx + 3 * kstride]))
              + rconst[t];
    float s1 = y, s2 = y * y;
    for (int o = 32; o; o >>= 1) { s1 += __shfl_down(s1, o); s2 += __shfl_down(s2, o); }
    if ((t & 63) == 0) { a1[t >> 6] = s1; a2[t >> 6] = s2; }
    __syncthreads();
    if (t == 0) {
        float S1 = a1[0] + a1[1] + a1[2] + a1[3];
        float S2 = a2[0] + a2[1] + a2[2] + a2[3];
        float mu = S1 / 256.f;
        mv[0] = mu;
        mv[1] = rsqrtf(S2 / 256.f - mu * mu + 1e-5f);
    }
    __syncthreads();
    float n = (y - mv[0]) * mv[1] * lnr_g[t] + lnr_b[t];
    sv[t] = 0.5f * n * (1.f + erff(n * 0.70710678118654752f));
    __syncthreads();

    {
        int e = t & 7, c = t >> 3;
        float part = 0.f;
#pragma unroll
        for (int jj = 0; jj < 8; ++jj)
            part += sv[c * 8 + jj] * Wr2[(c * 8 + jj) * E_NUM + e];
        part += __shfl_down(part, 8);
        part += __shfl_down(part, 16);
        part += __shfl_down(part, 32);
        if ((t & 63) < 8) wsum[t >> 6][e] = part;
    }
    __syncthreads();
    if (t < E_NUM)
        lg[t] = br2[t] + wsum[0][t] + wsum[1][t] + wsum[2][t] + wsum[3][t];
    __syncthreads();
    if (t == 0) {
        float v0 = -1e30f; int i0 = 0;
        for (int e = 0; e < E_NUM; ++e) if (lg[e] > v0) { v0 = lg[e]; i0 = e; }
        float v1 = -1e30f; int i1 = 0;
        for (int e = 0; e < E_NUM; ++e) if (e != i0 && lg[e] > v1) { v1 = lg[e]; i1 = e; }
        float e1 = expf(v1 - v0);
        pair_w[2 * b] = 1.f / (1.f + e1);
        pair_w[2 * b + 1] = e1 / (1.f + e1);
        sei[0] = i0; sei[1] = i1;
    }
    __syncthreads();
    if (t < 2) {
        int e = sei[t];
        int pos = atomicAdd(&counts[e * CPAD], 1);
        lists[e * B_TOK + pos] = 2 * b + t;
    }
}

// ---------------- sorted-row metadata (offs computed inline from padded counts)
__global__ void k_meta(const int* __restrict__ counts, const int* __restrict__ lists,
                       int* __restrict__ rowmap, int* __restrict__ row_e,
                       int* __restrict__ qof) {
    int q = blockIdx.x * 256 + threadIdx.x;
    int off_[E_NUM + 1]; off_[0] = 0;
#pragma unroll
    for (int i = 0; i < E_NUM; ++i) off_[i + 1] = off_[i] + counts[i * CPAD];
    int e = 0;
    while (e < E_NUM - 1 && q >= off_[e + 1]) ++e;
    int p = lists[e * B_TOK + (q - off_[e])];
    rowmap[q] = p;
    row_e[q] = e;
    qof[p] = q;
}

// ---------------- combine layer1 split-K partials + bias, LN + gelu -> bf16
__global__ void k_lngelu(const float* __restrict__ hidp, const float* __restrict__ b1,
                         unsigned short* __restrict__ hidb, const int* __restrict__ row_e,
                         const float* __restrict__ g, const float* __restrict__ bb) {
    int q = blockIdx.x, t = threadIdx.x;
    int e = row_e[q];
    const size_t st = (size_t)NPAIR * HID_DIM;
    size_t o0 = (size_t)q * HID_DIM + t;
    float y0 = hidp[o0] + hidp[o0 + st] + b1[e * HID_DIM + t];
    float y1 = hidp[o0 + 256] + hidp[o0 + 256 + st] + b1[e * HID_DIM + t + 256];
    float s1 = y0 + y1, s2 = y0 * y0 + y1 * y1;
    for (int o = 32; o; o >>= 1) { s1 += __shfl_down(s1, o); s2 += __shfl_down(s2, o); }
    __shared__ float a1[4], a2[4], mv[2];
    if ((t & 63) == 0) { a1[t >> 6] = s1; a2[t >> 6] = s2; }
    __syncthreads();
    if (t == 0) {
        float S1 = a1[0] + a1[1] + a1[2] + a1[3];
        float S2 = a2[0] + a2[1] + a2[2] + a2[3];
        float mu = S1 / 512.f;
        mv[0] = mu;
        mv[1] = rsqrtf(S2 / 512.f - mu * mu + 1e-5f);
    }
    __syncthreads();
    const float* ge = g + e * HID_DIM;
    const float* be = bb + e * HID_DIM;
    float mu = mv[0], ir = mv[1];
    float n0 = (y0 - mu) * ir * ge[t] + be[t];
    float n1 = (y1 - mu) * ir * ge[t + 256] + be[t + 256];
    unsigned short* orow = hidb + (size_t)q * HID_DIM;
    orow[t]       = f2bf(0.5f * n0 * (1.f + erff(n0 * 0.70710678118654752f)));
    orow[t + 256] = f2bf(0.5f * n1 * (1.f + erff(n1 * 0.70710678118654752f)));
}

// ---------------- final combine: out[o][token] = w0*act(sel[q0]) + w1*act(sel[q1])
__global__ void k_comb(const unsigned short* __restrict__ sel,
                       const int* __restrict__ qof, const float* __restrict__ pw,
                       float* __restrict__ out) {
    int b = blockIdx.x, o = blockIdx.y;
    int c = threadIdx.x * 4;
    int q0 = qof[2 * b], q1 = qof[2 * b + 1];
    float w0 = pw[2 * b], w1 = pw[2 * b + 1];
    u16x4 a = __builtin_nontemporal_load((const u16x4*)(sel + (size_t)q0 * 4096 + o * 1024 + c));
    u16x4 bq = __builtin_nontemporal_load((const u16x4*)(sel + (size_t)q1 * 4096 + o * 1024 + c));
    f32x4 r;
#pragma unroll
    for (int j = 0; j < 4; ++j)
        r[j] = w0 * apply_act(bf2f(a[j]), o) + w1 * apply_act(bf2f(bq[j]), o);
    __builtin_nontemporal_store(r, (f32x4*)(out + ((size_t)o * B_TOK + b) * D_DIM + c));
}

// ---------------- bf16 MFMA grouped GEMM, 128x128x32 tile, 4 waves
// R13-winning structure (NO grid-stride): NBUF=2, ONE barrier/iter, 32KB LDS,
// setprio, slot-XOR swizzle, ZPIN weight-resident XCD swizzle.
// MODE 1 adds an N-split: z = nh*nz_e + e, block covers cols
// [nh*N + n0, +128) of an Nfull-wide C/B (2MB weight panels -> L2-resident).
// MODE 1: Cb[q*ldc + col] = bf16(acc+bias)     (sorted rows; -> sel)
// MODE 4: Cf[(kh*B_TOK + row)*ldc] = acc       (dense rows, z = kh)
// MODE 5: Cf[(kh*NPAIR + q)*ldc]  = acc        (sorted rows, z = kh*8+e)
// MODE 8: Wfused-permuted write: A rows at e*512 offset, z = o*8+e
// MODE 9: fallback: atomic out[o][token] += pw*act(acc+bias)
template<int MODE, bool SPLIT, bool AGATHER, bool ZPIN>
__global__ __launch_bounds__(256)
void k_mm(const unsigned short* __restrict__ A, const unsigned short* __restrict__ Alo,
          int lda, int rowshift, int acol0,
          const unsigned short* __restrict__ Wp, const unsigned short* __restrict__ Wlo,
          size_t wstride,
          const float* __restrict__ bias, int bstride,
          float* __restrict__ Cf, unsigned short* __restrict__ Cb, int ldc,
          const int* __restrict__ counts, const int* __restrict__ rowmap, int Mfix,
          int N, int Nfull, int Kdim, int nz_e,
          float* __restrict__ outp, const float* __restrict__ pw) {
    const int gx = gridDim.x, gy = gridDim.y;
    unsigned fb = blockIdx.x + gx * (blockIdx.y + gy * blockIdx.z);
    int bx, byy, bz;
    if (ZPIN) {
        const unsigned nmn = gx * gy;
        unsigned xcd = fb & 7u, s = fb >> 3;
        bz  = xcd + 8u * (s / nmn);
        unsigned inner = s % nmn;
        bx  = inner % gx;
        byy = inner / gx;
    } else {
        unsigned xcd = fb & 7u, sb = fb >> 3;
        unsigned G = xcd + 8u * (sb / gx);
        bx  = sb % gx;
        byy = G % gy;
        bz  = G / gy;
    }

    const int e  = bz % nz_e;
    const int zq = bz / nz_e;
    int cnt = Mfix, base = 0;
    if (counts) {
        cnt = 0;
#pragma unroll
        for (int i = 0; i < E_NUM; ++i) {
            int c = counts[i * CPAD];
            if (i < e) base += c;
            if (i == e) cnt = c;
        }
    }
    const int m0 = byy * 128;
    if (m0 >= cnt) return;
    const int n0 = bx * 128;

    const size_t woff = (MODE == 8) ? (size_t)bz * wstride
                      : (MODE == 1 || MODE == 9) ? (size_t)e * wstride
                      : (size_t)e * wstride + (size_t)zq * Kdim * N;
    const unsigned short* W  = Wp + woff;
    const unsigned short* Wl = SPLIT ? (Wlo + woff) : nullptr;
    const float* bptr = (MODE == 1 || MODE == 9) ? bias + (size_t)e * bstride : nullptr;
    const int acol = acol0 + ((MODE == 4 || MODE == 5 || MODE == 8) ? zq * Kdim : 0);
    const int ncb  = (MODE == 1) ? zq * N : 0;   // N-split column base

    constexpr int ABUF = SPLIT ? 8192 : 4096;
    __shared__ unsigned short Alds[2][ABUF];
    __shared__ unsigned short Blds[2][ABUF];

    const int tid  = threadIdx.x;
    const int lane = tid & 63;
    const int wid  = tid >> 6;
    const int c0 = tid, c1 = tid + 256;
    const int r0 = c0 >> 2, r1 = c1 >> 2;

    auto aoff_of = [&](int r, int cq) -> size_t {
        int rr = m0 + r; if (rr >= cnt) rr = cnt - 1;
        int qg = base + rr;
        int row = AGATHER ? (rowmap[qg] >> rowshift)
                          : (MODE == 8 ? e * 512 + qg : qg);
        int slot = cq ^ ((r >> 1) & 3);
        return (size_t)row * lda + acol + (slot << 3);
    };
    size_t aoff0 = aoff_of(r0, c0 & 3);
    size_t aoff1 = aoff_of(r1, c1 & 3);
    const unsigned short* a0 = A + aoff0;
    const unsigned short* a1 = A + aoff1;
    const unsigned short* al0 = SPLIT ? Alo + aoff0 : nullptr;
    const unsigned short* al1 = SPLIT ? Alo + aoff1 : nullptr;
    size_t boff0 = ((size_t)(c0 >> 7) * Nfull + ncb + n0 + (c0 & 127)) * 8;
    size_t boff1 = ((size_t)(c1 >> 7) * Nfull + ncb + n0 + (c1 & 127)) * 8;
    const unsigned short* b0 = W + boff0;
    const unsigned short* b1 = W + boff1;
    const unsigned short* bl0 = SPLIT ? Wl + boff0 : nullptr;
    const unsigned short* bl1 = SPLIT ? Wl + boff1 : nullptr;

    const int d0 = c0 * 8, d1 = c1 * 8;
    const size_t bstep = (size_t)32 * Nfull;

    auto stage = [&](int buf) {
        glds16(a0, &Alds[buf][d0]);
        glds16(a1, &Alds[buf][d1]);
        glds16(b0, &Blds[buf][d0]);
        glds16(b1, &Blds[buf][d1]);
        if constexpr (SPLIT) {
            glds16(al0, &Alds[buf][4096 + d0]);
            glds16(al1, &Alds[buf][4096 + d1]);
            glds16(bl0, &Blds[buf][4096 + d0]);
            glds16(bl1, &Blds[buf][4096 + d1]);
            al0 += 32; al1 += 32; bl0 += bstep; bl1 += bstep;
        }
        a0 += 32; a1 += 32; b0 += bstep; b1 += bstep;
    };

    const int wm = wid >> 1, wn = wid & 1;
    const int lr = lane & 15, lg = lane >> 4;
    const int aslot = (lg ^ ((lr >> 1) & 3)) << 3;

    f32x4 acc[4][4];
#pragma unroll
    for (int i = 0; i < 4; ++i)
#pragma unroll
        for (int j = 0; j < 4; ++j) acc[i][j] = (f32x4){0.f, 0.f, 0.f, 0.f};

    auto compute = [&](int b) {
        bf16x8 af[4], bfr[4];
#pragma unroll
        for (int i = 0; i < 4; ++i)
            af[i] = *(const bf16x8*)&Alds[b][(wm * 64 + i * 16 + lr) * 32 + aslot];
#pragma unroll
        for (int i = 0; i < 4; ++i)
            bfr[i] = *(const bf16x8*)&Blds[b][((lg << 7) + wn * 64 + i * 16 + lr) * 8];
        __builtin_amdgcn_s_setprio(1);
#pragma unroll
        for (int mi = 0; mi < 4; ++mi)
#pragma unroll
            for (int ni = 0; ni < 4; ++ni)
                acc[mi][ni] = __builtin_amdgcn_mfma_f32_16x16x32_bf16(af[mi], bfr[ni], acc[mi][ni], 0, 0, 0);
        if constexpr (SPLIT) {
            bf16x8 afl[4], bfl[4];
#pragma unroll
            for (int i = 0; i < 4; ++i)
                afl[i] = *(const bf16x8*)&Alds[b][4096 + (wm * 64 + i * 16 + lr) * 32 + aslot];
#pragma unroll
            for (int i = 0; i < 4; ++i)
                bfl[i] = *(const bf16x8*)&Blds[b][4096 + ((lg << 7) + wn * 64 + i * 16 + lr) * 8];
#pragma unroll
            for (int mi = 0; mi < 4; ++mi)
#pragma unroll
                for (int ni = 0; ni < 4; ++ni) {
                    acc[mi][ni] = __builtin_amdgcn_mfma_f32_16x16x32_bf16(af[mi],  bfl[ni], acc[mi][ni], 0, 0, 0);
                    acc[mi][ni] = __builtin_amdgcn_mfma_f32_16x16x32_bf16(afl[mi], bfr[ni], acc[mi][ni], 0, 0, 0);
                }
        }
        __builtin_amdgcn_s_setprio(0);
        __builtin_amdgcn_sched_barrier(0);
    };

    const int niter = Kdim / 32;
    stage(0);
    asm volatile("s_waitcnt vmcnt(0)" ::: "memory");
    __builtin_amdgcn_s_barrier();
    __builtin_amdgcn_sched_barrier(0);
    int cur = 0;
    for (int it = 0; it < niter; ++it) {
        const bool more = (it + 1 < niter);
        if (more) stage(cur ^ 1);
        compute(cur);
        if (more) {
            asm volatile("s_waitcnt vmcnt(0)" ::: "memory");
            __builtin_amdgcn_s_barrier();
            __builtin_amdgcn_sched_barrier(0);
        }
        cur ^= 1;
    }

    float bv[4];
#pragma unroll
    for (int ni = 0; ni < 4; ++ni)
        bv[ni] = (MODE == 1 || MODE == 9) ? bptr[ncb + n0 + wn * 64 + ni * 16 + lr] : 0.f;

#pragma unroll
    for (int mi = 0; mi < 4; ++mi) {
        int rbase = m0 + wm * 64 + mi * 16 + lg * 4;
#pragma unroll
        for (int rg = 0; rg < 4; ++rg) {
            int r = rbase + rg;
            if (r >= cnt) continue;
            int q = base + r;
#pragma unroll
            for (int ni = 0; ni < 4; ++ni) {
                int col = ncb + n0 + wn * 64 + ni * 16 + lr;
                float v = acc[mi][ni][rg] + bv[ni];
                if (MODE == 1) {
                    Cb[(size_t)q * ldc + col] = f2bf(v);
                } else if (MODE == 4) {
                    Cf[((size_t)zq * B_TOK + q) * ldc + col] = v;
                } else if (MODE == 5) {
                    Cf[((size_t)zq * NPAIR + q) * ldc + col] = v;
                } else if (MODE == 8) {
                    Cb[((size_t)e * 64 * 4096 + (size_t)(r >> 3) * 4096 + acol + col) * 8
                       + (r & 7)] = f2bf(v);
                } else {  // MODE 9 fallback
                    int p = rowmap[q];
                    int o = col >> 10;
                    atomicAdd(outp + ((size_t)o * B_TOK + (p >> 1)) * D_DIM + (col & 1023),
                              pw[p] * apply_act(v, o));
                }
            }
        }
    }
}

extern "C" void kernel_launch(void* const* d_in, const int* in_sizes, int n_in,
                              void* d_out, int out_size, void* d_ws, size_t ws_size,
                              hipStream_t stream) {
    const float* h         = (const float*)d_in[0];
    const float* x         = (const float*)d_in[1];
    const int*   lidx      = (const int*)d_in[2];
    const float* layer_emb = (const float*)d_in[3];
    const float* phase_emb = (const float*)d_in[4];
    const float* Wr1       = (const float*)d_in[5];
    const float* br1       = (const float*)d_in[6];
    const float* lnr_g     = (const float*)d_in[7];
    const float* lnr_b     = (const float*)d_in[8];
    const float* Wr2       = (const float*)d_in[9];
    const float* br2       = (const float*)d_in[10];
    const float* W1        = (const float*)d_in[11];
    const float* b1        = (const float*)d_in[12];
    const float* ln1g      = (const float*)d_in[13];
    const float* ln1b      = (const float*)d_in[14];
    const float* W2        = (const float*)d_in[15];
    const float* b2        = (const float*)d_in[16];
    const float* Wa        = (const float*)d_in[17];
    const float* ba        = (const float*)d_in[18];
    const float* Wb_       = (const float*)d_in[19];
    const float* bbv       = (const float*)d_in[20];
    const float* Wg        = (const float*)d_in[21];
    const float* bg        = (const float*)d_in[22];
    const float* Wv        = (const float*)d_in[23];
    const float* bv        = (const float*)d_in[24];
    float* out = (float*)d_out;

    char* ws = (char*)d_ws;
    size_t off = 0;
    auto alloc = [&](size_t nb) { void* p = ws + off; off = (off + nb + 255) & ~(size_t)255; return p; };
    float*          rconstp = (float*)alloc(RH_DIM * 4);
    float*          pair_w  = (float*)alloc(NPAIR * 4);
    int*            counts  = (int*)alloc(E_NUM * CPAD * 4);                       // padded: 1KB
    int*            lists   = (int*)alloc((size_t)E_NUM * B_TOK * 4);
    int*            rowmap  = (int*)alloc(NPAIR * 4);
    int*            row_e   = (int*)alloc(NPAIR * 4);
    int*            qof     = (int*)alloc(NPAIR * 4);
    float*          bfused  = (float*)alloc((size_t)E_NUM * 4096 * 4);             // 128 KB
    unsigned short* hx_hi   = (unsigned short*)alloc((size_t)B_TOK * 2048 * 2);    // 16 MiB
    unsigned short* hid_bf  = (unsigned short*)alloc((size_t)NPAIR * HID_DIM * 2); // 8 MiB
    unsigned short* wsc_hi  = (unsigned short*)alloc((size_t)8 * 2048 * HID_DIM * 2); // 16 MiB
    unsigned short* wsc_lo  = (unsigned short*)alloc((size_t)2048 * RH_DIM * 2);   // 1 MiB
    unsigned short* Wfused  = (unsigned short*)alloc((size_t)E_NUM * 64 * 4096 * 8 * 2); // 32 MiB
    unsigned short* sel     = (unsigned short*)alloc((size_t)NPAIR * 4096 * 2);    // 64 MiB
    char*           scratch = (char*)alloc((size_t)34 << 20);                      // 34 MiB
    const bool use_sel = (off <= ws_size);
    // aliases (disjoint lifetimes):
    unsigned short* wsc4  = sel;                                         // 64M: layer3 W conv, dead before sel write
    unsigned short* W2bf  = (unsigned short*)scratch;                    // 33.5M, written after hidp dead
    unsigned short* hx_lo = (unsigned short*)scratch;                    // 16M, dead after routing mm
    float*          Pf    = (float*)(scratch + ((size_t)17 << 20));      // 16M, dead after k_route
    float*          hidp  = (float*)scratch;                             // 33.6M, dead after k_lngelu

    if (!use_sel) (void)hipMemsetAsync(d_out, 0, (size_t)out_size * 4, stream);
    (void)hipMemsetAsync(counts, 0, E_NUM * CPAD * 4, stream);

    // ---- routing path: split-K x4 partials (deterministic fixed-order combine)
    k_hxbf<<<4096, 256, 0, stream>>>(h, x, hx_hi, hx_lo);
    k_convW<true><<<dim3(1, 256, 1), 256, 0, stream>>>(Wr1, nullptr, nullptr, nullptr,
                                                       wsc_hi, wsc_lo, 2048, RH_DIM, 1);
    k_rconst<<<1, 256, 0, stream>>>(layer_emb, phase_emb, lidx, Wr1, br1, rconstp);
    k_mm<4, true, false, false><<<dim3(2, 32, 4), 256, 0, stream>>>(
        hx_hi, hx_lo, 2048, 0, 0, wsc_hi, wsc_lo, 0, nullptr, 0,
        Pf, nullptr, RH_DIM, nullptr, nullptr, B_TOK,
        RH_DIM, RH_DIM, 512, 1, nullptr, nullptr);
    k_route<<<B_TOK, 256, 0, stream>>>(Pf, rconstp, lnr_g, lnr_b, Wr2, br2,
                                       pair_w, lists, counts);
    k_meta<<<NPAIR / 256, 256, 0, stream>>>(counts, lists, rowmap, row_e, qof);

    // ---- layer1 (split-K x2, sorted C): hidp[kh][q](512) = hx[token] @ W1[e]
    k_convW<false><<<dim3(2, 256, 8), 256, 0, stream>>>(W1, nullptr, nullptr, nullptr,
                                                        wsc_hi, nullptr, 2048, HID_DIM, 8);
    k_mm<5, false, true, true><<<dim3(4, 32, 16), 256, 0, stream>>>(
        hx_hi, nullptr, 2048, 1, 0, wsc_hi, nullptr, (size_t)2048 * HID_DIM, nullptr, 0,
        hidp, nullptr, HID_DIM, counts, rowmap, 0,
        HID_DIM, HID_DIM, 1024, 8, nullptr, nullptr);
    k_lngelu<<<NPAIR, 256, 0, stream>>>(hidp, b1, hid_bf, row_e, ln1g, ln1b);

    // ---- Wfused precompute: Wfused[e] = W2[e] (512x4096, o-sliced) @ Wo[e]
    k_cvtflat<<<8192, 256, 0, stream>>>(W2, W2bf);
    k_convW<false><<<dim3(4, 128, 32), 256, 0, stream>>>(
        Wa, Wb_, Wg, Wv, wsc4, nullptr, D_DIM, D_DIM, 8);
    k_bfuse<<<dim3(4, 32), 256, 0, stream>>>(b2, ba, bbv, bg, bv, wsc4, bfused);
    k_mm<8, false, false, true><<<dim3(8, 4, 32), 256, 0, stream>>>(
        W2bf, nullptr, 4096, 0, 0,
        wsc4, nullptr, (size_t)D_DIM * D_DIM, nullptr, 0,
        nullptr, Wfused, 0, nullptr, nullptr, 512,
        D_DIM, D_DIM, D_DIM, 8, nullptr, nullptr);

    // ---- fused layer2+3 (N-split x2, no grid-stride): z = nh*8+e
    if (use_sel) {
        k_mm<1, false, false, true><<<dim3(16, 32, 16), 256, 0, stream>>>(
            hid_bf, nullptr, HID_DIM, 0, 0,
            Wfused, nullptr, (size_t)64 * 4096 * 8, bfused, 4096,
            nullptr, sel, 4096, counts, rowmap, 0,
            2048, 4096, HID_DIM, 8, nullptr, nullptr);
        k_comb<<<dim3(B_TOK, 4), 256, 0, stream>>>(sel, qof, pair_w, out);
    } else {
        k_mm<9, false, false, true><<<dim3(32, 32, 8), 256, 0, stream>>>(
            hid_bf, nullptr, HID_DIM, 0, 0,
            Wfused, nullptr, (size_t)64 * 4096 * 8, bfused, 4096,
            nullptr, nullptr, 0, counts, rowmap, 0,
            4096, 4096, HID_DIM, 8, out, pair_w);
    }
}